// Round 9
// baseline (24.825 us; speedup 1.0000x reference)
//
#include <hip/hip_runtime.h>
#include <math.h>

// ---------------------------------------------------------------------------
// ANI NNP fully fused, ONE kernel node, 256 blocks x 1024 threads.
// Block = (batch, 4 atoms).
// NEW (R9): waves 4-15 prefetch their layer-1 W1 chunk (32 regs/thread) at
// kernel start, overlapping the AEV phase (computed entirely by waves 0-3).
// Layer 1 keeps W1 read once per block (R8); first 8 r4-chunks of q>=4 come
// from the held registers.
// Cross-block reduction via release/acquire flags in d_ws (verified R6-R8).
// ---------------------------------------------------------------------------

#define NB 32
#define NA 32
#define FLAG_MAGIC 0x3C96A5F1

__device__ __forceinline__ float celu01(float x) {
    return x > 0.0f ? x : 0.1f * expm1f(x * 10.0f);
}

__global__ __launch_bounds__(1024)
void fused_kernel(const int* __restrict__ species, const float* __restrict__ coords,
                  const int* __restrict__ belong, const float* __restrict__ approx,
                  const float* __restrict__ W1, const float* __restrict__ b1,
                  const float* __restrict__ W2, const float* __restrict__ b2,
                  const float* __restrict__ W3, const float* __restrict__ b3,
                  const float* __restrict__ W4, const float* __restrict__ b4,
                  float* __restrict__ partial, int* __restrict__ flags,
                  float* __restrict__ out) {
    const int blk = blockIdx.x;
    const int b = blk >> 3, grp = blk & 7;     // 4 atoms: ia = grp*4 + li
    const int t = threadIdx.x;
    const float PI = 3.14159265358979323846f;

    __shared__ float cx[32], cy[32], cz[32];
    __shared__ int   spec[32];
    __shared__ float dists[4][32], fcas[4][32], uxs[4][32], uys[4][32], uzs[4][32];
    __shared__ int   nbr[4][32];
    __shared__ int   cnt[4];
    __shared__ __align__(16) float aev[4][1284];   // rad 0..127 | ang 128..1279 | approx 1280
    __shared__ float part[16][4][64];              // [q][atom][col] layer-1 partials
    __shared__ float h1[4][64], h2[4][32], h3[4][16];
    __shared__ float czl[8], szl[8];
    __shared__ float evals[4];
    __shared__ float peers[8];

    // ---- W1 register prefetch (waves 4-15): issue loads FIRST, use in layer 1.
    // Rows q*80 .. q*80+31 (r4-chunks q*20 .. q*20+7), column c = t&63.
    float w1h0=0,w1h1=0,w1h2=0,w1h3=0,w1h4=0,w1h5=0,w1h6=0,w1h7=0,
          w1h8=0,w1h9=0,w1h10=0,w1h11=0,w1h12=0,w1h13=0,w1h14=0,w1h15=0,
          w1h16=0,w1h17=0,w1h18=0,w1h19=0,w1h20=0,w1h21=0,w1h22=0,w1h23=0,
          w1h24=0,w1h25=0,w1h26=0,w1h27=0,w1h28=0,w1h29=0,w1h30=0,w1h31=0;
    if (t >= 256) {
        const int c = t & 63, q = t >> 6;
        const float* Wp = W1 + (size_t)(q * 80) * 64 + c;
        w1h0  = Wp[ 0*64]; w1h1  = Wp[ 1*64]; w1h2  = Wp[ 2*64]; w1h3  = Wp[ 3*64];
        w1h4  = Wp[ 4*64]; w1h5  = Wp[ 5*64]; w1h6  = Wp[ 6*64]; w1h7  = Wp[ 7*64];
        w1h8  = Wp[ 8*64]; w1h9  = Wp[ 9*64]; w1h10 = Wp[10*64]; w1h11 = Wp[11*64];
        w1h12 = Wp[12*64]; w1h13 = Wp[13*64]; w1h14 = Wp[14*64]; w1h15 = Wp[15*64];
        w1h16 = Wp[16*64]; w1h17 = Wp[17*64]; w1h18 = Wp[18*64]; w1h19 = Wp[19*64];
        w1h20 = Wp[20*64]; w1h21 = Wp[21*64]; w1h22 = Wp[22*64]; w1h23 = Wp[23*64];
        w1h24 = Wp[24*64]; w1h25 = Wp[25*64]; w1h26 = Wp[26*64]; w1h27 = Wp[27*64];
        w1h28 = Wp[28*64]; w1h29 = Wp[29*64]; w1h30 = Wp[30*64]; w1h31 = Wp[31*64];
    }
    __builtin_amdgcn_sched_barrier(0);   // pin prefetch issue before AEV phase

    if (t < 32) {
        int g = b * NA + t;
        cx[t] = coords[g*3+0]; cy[t] = coords[g*3+1]; cz[t] = coords[g*3+2];
        spec[t] = species[g] + (belong[g]-1)*4;
    }
    if (t >= 64 && t < 72) {
        int z = t - 64;
        float th = PI/16.0f + (float)z * (PI/8.0f);
        czl[z] = cosf(th); szl[z] = sinf(th);
    }
    for (int idx = t; idx < 4*1284; idx += 1024) ((float*)aev)[idx] = 0.0f;
    __syncthreads();

    // ---- phase 1 (threads 0..127): distances, radial, neighbor compaction ----
    if (t < 128) {
        const int li = t >> 5, j = t & 31;
        const int ia = grp*4 + li;
        float dx = cx[j]-cx[ia], dy = cy[j]-cy[ia], dz = cz[j]-cz[ia];
        float d2 = dx*dx + dy*dy + dz*dz;
        float d = sqrtf(d2 > 0.0f ? d2 : 1.0f);   // mirror reference safe-sqrt
        float inv = 1.0f / d;
        dists[li][j] = d;
        uxs[li][j] = dx*inv; uys[li][j] = dy*inv; uzs[li][j] = dz*inv;
        bool self = (j == ia);
        float fca = (!self && d <= 3.5f) ? (0.5f*cosf(PI*d/3.5f)+0.5f) : 0.0f;
        fcas[li][j] = fca;

        if (!self && d <= 5.2f) {                  // radial
            float f = 0.5f*cosf(PI*d/5.2f) + 0.5f;
            int base = spec[j]*16;
            #pragma unroll
            for (int r = 0; r < 16; ++r) {
                float dd = d - (0.9f + 0.26875f*(float)r);
                atomicAdd(&aev[li][base+r], 0.25f*expf(-16.0f*dd*dd)*f);
            }
        }
        // compact neighbors with fca>0 (deterministic, ballot-ordered)
        bool act = (fca > 0.0f);
        unsigned long long mask = __ballot(act);
        unsigned int half = (t & 32) ? (unsigned int)(mask >> 32)
                                     : (unsigned int)(mask & 0xFFFFFFFFull);
        int l31 = t & 31;
        int pos = __popc(half & ((1u << l31) - 1u));
        if (act) nbr[li][pos] = j;
        if (l31 == 0) cnt[li] = __popc(half);
    }
    __syncthreads();

    // ---- phase 2: angular over compacted unordered pairs; waves 0-3 only ----
    if (t < 256) {
        const int li = t >> 6, lane = t & 63;
        const int n2 = cnt[li];
        const int npairs = n2*(n2-1)/2;
        for (int p = lane; p < npairs; p += 64) {
            int m = 0, rem = p, rl = n2 - 1;
            while (rem >= rl) { rem -= rl; --rl; ++m; }
            int n = m + 1 + rem;
            int j = nbr[li][m], k = nbr[li][n];

            float wjk = fcas[li][j] * fcas[li][k];
            float cd = uxs[li][j]*uxs[li][k] + uys[li][j]*uys[li][k] + uzs[li][j]*uzs[li][k];
            cd = fminf(fmaxf(cd, -1.0f), 1.0f);
            float cth = 0.95f * cd;                 // cos(theta)
            float sth = sqrtf(1.0f - cth*cth);      // sin(theta) >= 0
            float ravg = 0.5f * (dists[li][j] + dists[li][k]);

            float f1[8];
            #pragma unroll
            for (int z = 0; z < 8; ++z) {
                float base = 0.5f*(1.0f + cth*czl[z] + sth*szl[z]);
                float x2 = base*base; x2 = x2*x2; x2 = x2*x2; x2 = x2*x2; x2 = x2*x2;
                f1[z] = x2;                          // ^32
            }
            int sj = spec[j], sk = spec[k];
            int smin = sj < sk ? sj : sk, smax = sj < sk ? sk : sj;
            int pp = 8*smin - (smin*(smin-1))/2 + (smax - smin);
            float w2 = 2.0f * wjk;
            #pragma unroll
            for (int a = 0; a < 4; ++a) {
                float da = ravg - (0.9f + 0.65f*(float)a);
                float f2 = expf(-8.0f*da*da) * w2;
                int bb = 128 + pp*32 + a*8;
                #pragma unroll
                for (int z = 0; z < 8; ++z) atomicAdd(&aev[li][bb+z], f2*f1[z]);
            }
        }
    }
    if (t < 4) aev[t][1280] = approx[b*NA + grp*4 + t];
    __syncthreads();

    // ---- layer 1: thread (q = K-chunk 0..15, c = col 0..63); W1 read once/block.
    //      q>=4: first 8 r4-chunks use prefetched registers. ----
    {
        const int c = t & 63, q = t >> 6;          // q in 0..15, 80 K-rows each
        float a0 = 0.0f, a1 = 0.0f, a2 = 0.0f, a3 = 0.0f;
        const float4* x0 = (const float4*)(&aev[0][0]);
        const float4* x1 = (const float4*)(&aev[1][0]);
        const float4* x2 = (const float4*)(&aev[2][0]);
        const float4* x3 = (const float4*)(&aev[3][0]);
        const int r4beg = q * 20;

        if (t >= 256) {
            // held-register portion: r4 = r4beg+0 .. r4beg+7
            #define HELD_STEP(RR, WA, WB, WC, WD)                                  \
            {   const int r4 = r4beg + RR;                                         \
                float4 v0 = x0[r4], v1 = x1[r4], v2 = x2[r4], v3 = x3[r4];         \
                a0 = fmaf(v0.x, WA, a0); a0 = fmaf(v0.y, WB, a0);                  \
                a0 = fmaf(v0.z, WC, a0); a0 = fmaf(v0.w, WD, a0);                  \
                a1 = fmaf(v1.x, WA, a1); a1 = fmaf(v1.y, WB, a1);                  \
                a1 = fmaf(v1.z, WC, a1); a1 = fmaf(v1.w, WD, a1);                  \
                a2 = fmaf(v2.x, WA, a2); a2 = fmaf(v2.y, WB, a2);                  \
                a2 = fmaf(v2.z, WC, a2); a2 = fmaf(v2.w, WD, a2);                  \
                a3 = fmaf(v3.x, WA, a3); a3 = fmaf(v3.y, WB, a3);                  \
                a3 = fmaf(v3.z, WC, a3); a3 = fmaf(v3.w, WD, a3); }
            HELD_STEP(0, w1h0,  w1h1,  w1h2,  w1h3)
            HELD_STEP(1, w1h4,  w1h5,  w1h6,  w1h7)
            HELD_STEP(2, w1h8,  w1h9,  w1h10, w1h11)
            HELD_STEP(3, w1h12, w1h13, w1h14, w1h15)
            HELD_STEP(4, w1h16, w1h17, w1h18, w1h19)
            HELD_STEP(5, w1h20, w1h21, w1h22, w1h23)
            HELD_STEP(6, w1h24, w1h25, w1h26, w1h27)
            HELD_STEP(7, w1h28, w1h29, w1h30, w1h31)
            #undef HELD_STEP
            #pragma unroll 4
            for (int rr = 8; rr < 20; ++rr) {
                const int r4 = r4beg + rr;
                const int rb = r4 * 4;
                float w1a = W1[(rb+0)*64 + c];
                float w1b = W1[(rb+1)*64 + c];
                float w1c = W1[(rb+2)*64 + c];
                float w1d = W1[(rb+3)*64 + c];
                float4 v0 = x0[r4], v1 = x1[r4], v2 = x2[r4], v3 = x3[r4];
                a0 = fmaf(v0.x, w1a, a0); a0 = fmaf(v0.y, w1b, a0);
                a0 = fmaf(v0.z, w1c, a0); a0 = fmaf(v0.w, w1d, a0);
                a1 = fmaf(v1.x, w1a, a1); a1 = fmaf(v1.y, w1b, a1);
                a1 = fmaf(v1.z, w1c, a1); a1 = fmaf(v1.w, w1d, a1);
                a2 = fmaf(v2.x, w1a, a2); a2 = fmaf(v2.y, w1b, a2);
                a2 = fmaf(v2.z, w1c, a2); a2 = fmaf(v2.w, w1d, a2);
                a3 = fmaf(v3.x, w1a, a3); a3 = fmaf(v3.y, w1b, a3);
                a3 = fmaf(v3.z, w1c, a3); a3 = fmaf(v3.w, w1d, a3);
            }
        } else {
            #pragma unroll 4
            for (int rr = 0; rr < 20; ++rr) {
                const int r4 = r4beg + rr;
                const int rb = r4 * 4;
                float w1a = W1[(rb+0)*64 + c];
                float w1b = W1[(rb+1)*64 + c];
                float w1c = W1[(rb+2)*64 + c];
                float w1d = W1[(rb+3)*64 + c];
                float4 v0 = x0[r4], v1 = x1[r4], v2 = x2[r4], v3 = x3[r4];
                a0 = fmaf(v0.x, w1a, a0); a0 = fmaf(v0.y, w1b, a0);
                a0 = fmaf(v0.z, w1c, a0); a0 = fmaf(v0.w, w1d, a0);
                a1 = fmaf(v1.x, w1a, a1); a1 = fmaf(v1.y, w1b, a1);
                a1 = fmaf(v1.z, w1c, a1); a1 = fmaf(v1.w, w1d, a1);
                a2 = fmaf(v2.x, w1a, a2); a2 = fmaf(v2.y, w1b, a2);
                a2 = fmaf(v2.z, w1c, a2); a2 = fmaf(v2.w, w1d, a2);
                a3 = fmaf(v3.x, w1a, a3); a3 = fmaf(v3.y, w1b, a3);
                a3 = fmaf(v3.z, w1c, a3); a3 = fmaf(v3.w, w1d, a3);
            }
        }
        part[q][0][c] = a0; part[q][1][c] = a1;
        part[q][2][c] = a2; part[q][3][c] = a3;
    }
    __syncthreads();
    if (t < 256) {
        const int c = t & 63, w = t >> 6;
        float acc = b1[c] + aev[w][1280] * W1[1280*64 + c];
        #pragma unroll
        for (int q = 0; q < 16; q += 4)
            acc += ((part[q][w][c] + part[q+1][w][c]) + (part[q+2][w][c] + part[q+3][w][c]));
        h1[w][c] = celu01(acc);
    }
    __syncthreads();

    if (t < 128) {            // layer 2: 4 atoms x 32 cols
        int a = t >> 5, cc = t & 31;
        float s = b2[cc];
        #pragma unroll 8
        for (int r = 0; r < 64; ++r) s = fmaf(h1[a][r], W2[r*32 + cc], s);
        h2[a][cc] = celu01(s);
    }
    __syncthreads();

    if (t < 64) {             // layer 3: 4 x 16
        int a = t >> 4, cc = t & 15;
        float s = b3[cc];
        #pragma unroll
        for (int r = 0; r < 32; ++r) s = fmaf(h2[a][r], W3[r*16 + cc], s);
        h3[a][cc] = celu01(s);
    }
    __syncthreads();

    if (t < 4) {              // layer 4 per atom
        float e = b4[0];
        #pragma unroll
        for (int r = 0; r < 16; ++r) e = fmaf(h3[t][r], W4[r], e);
        evals[t] = e;
    }
    __syncthreads();

    // ---- cross-block reduction via device-scope flags in d_ws ----
    if (grp != 0) {
        if (t == 0) {
            float v = (evals[0]+evals[1]) + (evals[2]+evals[3]);
            __hip_atomic_store(&partial[blk], v, __ATOMIC_RELAXED, __HIP_MEMORY_SCOPE_AGENT);
            __hip_atomic_store(&flags[blk], FLAG_MAGIC, __ATOMIC_RELEASE, __HIP_MEMORY_SCOPE_AGENT);
        }
    } else {
        if (t == 0) peers[0] = (evals[0]+evals[1]) + (evals[2]+evals[3]);
        if (t >= 1 && t < 8) {
            int src = blk + t;   // b*8 + t
            while (__hip_atomic_load(&flags[src], __ATOMIC_ACQUIRE,
                                     __HIP_MEMORY_SCOPE_AGENT) != FLAG_MAGIC) { }
            peers[t] = __hip_atomic_load(&partial[src], __ATOMIC_RELAXED,
                                         __HIP_MEMORY_SCOPE_AGENT);
            __hip_atomic_store(&flags[src], 0, __ATOMIC_RELAXED,
                               __HIP_MEMORY_SCOPE_AGENT);   // known state for next call
        }
        __syncthreads();
        if (t == 0) {
            float s = ((peers[0]+peers[1]) + (peers[2]+peers[3]))
                    + ((peers[4]+peers[5]) + (peers[6]+peers[7]));
            out[b] = s;
        }
    }
}

extern "C" void kernel_launch(void* const* d_in, const int* in_sizes, int n_in,
                              void* d_out, int out_size, void* d_ws, size_t ws_size,
                              hipStream_t stream) {
    (void)in_sizes; (void)n_in; (void)ws_size; (void)out_size;
    const int*   species = (const int*)d_in[0];
    const float* coords  = (const float*)d_in[1];
    const int*   belong  = (const int*)d_in[2];
    const float* approx  = (const float*)d_in[3];
    const float* W1 = (const float*)d_in[4];  const float* b1 = (const float*)d_in[5];
    const float* W2 = (const float*)d_in[6];  const float* b2 = (const float*)d_in[7];
    const float* W3 = (const float*)d_in[8];  const float* b3 = (const float*)d_in[9];
    const float* W4 = (const float*)d_in[10]; const float* b4 = (const float*)d_in[11];
    float* partial = (float*)d_ws;                 // 256 floats
    int*   flags   = ((int*)d_ws) + 256;           // 256 ints
    float* out     = (float*)d_out;

    fused_kernel<<<NB * 8, 1024, 0, stream>>>(species, coords, belong, approx,
                                              W1, b1, W2, b2, W3, b3, W4, b4,
                                              partial, flags, out);
}

// Round 10
// 23.699 us; speedup vs baseline: 1.0475x; 1.0475x over previous
//
#include <hip/hip_runtime.h>
#include <math.h>

// ---------------------------------------------------------------------------
// ANI NNP fully fused, ONE kernel node, 256 blocks x 1024 threads.
// Block = (batch, 4 atoms). Layer 1 structured so each W1 element is read
// exactly ONCE per block (thread = (K-chunk q, column c), 4 atom-accumulators,
// aev via LDS float4 broadcast) -> minimal L2 traffic (84 MB aggregate).
// [R9 post-mortem: W1 register-prefetch across the AEV phase REGRESSED
//  (23.8 -> 24.8 us); 16 waves/CU already hide L2 latency. Reverted to R8.]
// Cross-block reduction via release/acquire flags in d_ws (verified R6-R8).
// ---------------------------------------------------------------------------

#define NB 32
#define NA 32
#define FLAG_MAGIC 0x3C96A5F1

__device__ __forceinline__ float celu01(float x) {
    return x > 0.0f ? x : 0.1f * expm1f(x * 10.0f);
}

__global__ __launch_bounds__(1024)
void fused_kernel(const int* __restrict__ species, const float* __restrict__ coords,
                  const int* __restrict__ belong, const float* __restrict__ approx,
                  const float* __restrict__ W1, const float* __restrict__ b1,
                  const float* __restrict__ W2, const float* __restrict__ b2,
                  const float* __restrict__ W3, const float* __restrict__ b3,
                  const float* __restrict__ W4, const float* __restrict__ b4,
                  float* __restrict__ partial, int* __restrict__ flags,
                  float* __restrict__ out) {
    const int blk = blockIdx.x;
    const int b = blk >> 3, grp = blk & 7;     // 4 atoms: ia = grp*4 + li
    const int t = threadIdx.x;
    const float PI = 3.14159265358979323846f;

    __shared__ float cx[32], cy[32], cz[32];
    __shared__ int   spec[32];
    __shared__ float dists[4][32], fcas[4][32], uxs[4][32], uys[4][32], uzs[4][32];
    __shared__ int   nbr[4][32];
    __shared__ int   cnt[4];
    __shared__ __align__(16) float aev[4][1284];   // rad 0..127 | ang 128..1279 | approx 1280
    __shared__ float part[16][4][64];              // [q][atom][col] layer-1 partials
    __shared__ float h1[4][64], h2[4][32], h3[4][16];
    __shared__ float czl[8], szl[8];
    __shared__ float evals[4];
    __shared__ float peers[8];

    if (t < 32) {
        int g = b * NA + t;
        cx[t] = coords[g*3+0]; cy[t] = coords[g*3+1]; cz[t] = coords[g*3+2];
        spec[t] = species[g] + (belong[g]-1)*4;
    }
    if (t < 8) {
        float th = PI/16.0f + (float)t * (PI/8.0f);
        czl[t] = cosf(th); szl[t] = sinf(th);
    }
    for (int idx = t; idx < 4*1284; idx += 1024) ((float*)aev)[idx] = 0.0f;
    __syncthreads();

    // ---- phase 1 (threads 0..127): distances, radial, neighbor compaction ----
    if (t < 128) {
        const int li = t >> 5, j = t & 31;
        const int ia = grp*4 + li;
        float dx = cx[j]-cx[ia], dy = cy[j]-cy[ia], dz = cz[j]-cz[ia];
        float d2 = dx*dx + dy*dy + dz*dz;
        float d = sqrtf(d2 > 0.0f ? d2 : 1.0f);   // mirror reference safe-sqrt
        float inv = 1.0f / d;
        dists[li][j] = d;
        uxs[li][j] = dx*inv; uys[li][j] = dy*inv; uzs[li][j] = dz*inv;
        bool self = (j == ia);
        float fca = (!self && d <= 3.5f) ? (0.5f*cosf(PI*d/3.5f)+0.5f) : 0.0f;
        fcas[li][j] = fca;

        if (!self && d <= 5.2f) {                  // radial
            float f = 0.5f*cosf(PI*d/5.2f) + 0.5f;
            int base = spec[j]*16;
            #pragma unroll
            for (int r = 0; r < 16; ++r) {
                float dd = d - (0.9f + 0.26875f*(float)r);
                atomicAdd(&aev[li][base+r], 0.25f*expf(-16.0f*dd*dd)*f);
            }
        }
        // compact neighbors with fca>0 (deterministic, ballot-ordered)
        bool act = (fca > 0.0f);
        unsigned long long mask = __ballot(act);
        unsigned int half = (t & 32) ? (unsigned int)(mask >> 32)
                                     : (unsigned int)(mask & 0xFFFFFFFFull);
        int l31 = t & 31;
        int pos = __popc(half & ((1u << l31) - 1u));
        if (act) nbr[li][pos] = j;
        if (l31 == 0) cnt[li] = __popc(half);
    }
    __syncthreads();

    // ---- phase 2: angular over compacted unordered pairs; 256 lanes per atom ----
    {
        const int li = t >> 8, lane = t & 255;
        const int n2 = cnt[li];
        const int npairs = n2*(n2-1)/2;
        for (int p = lane; p < npairs; p += 256) {
            int m = 0, rem = p, rl = n2 - 1;
            while (rem >= rl) { rem -= rl; --rl; ++m; }
            int n = m + 1 + rem;
            int j = nbr[li][m], k = nbr[li][n];

            float wjk = fcas[li][j] * fcas[li][k];
            float cd = uxs[li][j]*uxs[li][k] + uys[li][j]*uys[li][k] + uzs[li][j]*uzs[li][k];
            cd = fminf(fmaxf(cd, -1.0f), 1.0f);
            float cth = 0.95f * cd;                 // cos(theta)
            float sth = sqrtf(1.0f - cth*cth);      // sin(theta) >= 0
            float ravg = 0.5f * (dists[li][j] + dists[li][k]);

            float f1[8];
            #pragma unroll
            for (int z = 0; z < 8; ++z) {
                float base = 0.5f*(1.0f + cth*czl[z] + sth*szl[z]);
                float x2 = base*base; x2 = x2*x2; x2 = x2*x2; x2 = x2*x2; x2 = x2*x2;
                f1[z] = x2;                          // ^32
            }
            int sj = spec[j], sk = spec[k];
            int smin = sj < sk ? sj : sk, smax = sj < sk ? sk : sj;
            int pp = 8*smin - (smin*(smin-1))/2 + (smax - smin);
            float w2 = 2.0f * wjk;
            #pragma unroll
            for (int a = 0; a < 4; ++a) {
                float da = ravg - (0.9f + 0.65f*(float)a);
                float f2 = expf(-8.0f*da*da) * w2;
                int bb = 128 + pp*32 + a*8;
                #pragma unroll
                for (int z = 0; z < 8; ++z) atomicAdd(&aev[li][bb+z], f2*f1[z]);
            }
        }
    }
    if (t < 4) aev[t][1280] = approx[b*NA + grp*4 + t];
    __syncthreads();

    // ---- layer 1: thread (q = K-chunk 0..15, c = col 0..63); W1 read once/block ----
    {
        const int c = t & 63, q = t >> 6;          // q in 0..15, 80 K-rows each
        float a0 = 0.0f, a1 = 0.0f, a2 = 0.0f, a3 = 0.0f;
        const float4* x0 = (const float4*)(&aev[0][0]);
        const float4* x1 = (const float4*)(&aev[1][0]);
        const float4* x2 = (const float4*)(&aev[2][0]);
        const float4* x3 = (const float4*)(&aev[3][0]);
        const int r4beg = q * 20;
        #pragma unroll 4
        for (int rr = 0; rr < 20; ++rr) {
            const int r4 = r4beg + rr;
            const int rb = r4 * 4;
            float w1a = W1[(rb+0)*64 + c];
            float w1b = W1[(rb+1)*64 + c];
            float w1c = W1[(rb+2)*64 + c];
            float w1d = W1[(rb+3)*64 + c];
            float4 v0 = x0[r4], v1 = x1[r4], v2 = x2[r4], v3 = x3[r4];
            a0 = fmaf(v0.x, w1a, a0); a0 = fmaf(v0.y, w1b, a0);
            a0 = fmaf(v0.z, w1c, a0); a0 = fmaf(v0.w, w1d, a0);
            a1 = fmaf(v1.x, w1a, a1); a1 = fmaf(v1.y, w1b, a1);
            a1 = fmaf(v1.z, w1c, a1); a1 = fmaf(v1.w, w1d, a1);
            a2 = fmaf(v2.x, w1a, a2); a2 = fmaf(v2.y, w1b, a2);
            a2 = fmaf(v2.z, w1c, a2); a2 = fmaf(v2.w, w1d, a2);
            a3 = fmaf(v3.x, w1a, a3); a3 = fmaf(v3.y, w1b, a3);
            a3 = fmaf(v3.z, w1c, a3); a3 = fmaf(v3.w, w1d, a3);
        }
        part[q][0][c] = a0; part[q][1][c] = a1;
        part[q][2][c] = a2; part[q][3][c] = a3;
    }
    __syncthreads();
    if (t < 256) {
        const int c = t & 63, w = t >> 6;
        float acc = b1[c] + aev[w][1280] * W1[1280*64 + c];
        #pragma unroll
        for (int q = 0; q < 16; q += 4)
            acc += ((part[q][w][c] + part[q+1][w][c]) + (part[q+2][w][c] + part[q+3][w][c]));
        h1[w][c] = celu01(acc);
    }
    __syncthreads();

    if (t < 128) {            // layer 2: 4 atoms x 32 cols
        int a = t >> 5, cc = t & 31;
        float s = b2[cc];
        #pragma unroll 8
        for (int r = 0; r < 64; ++r) s = fmaf(h1[a][r], W2[r*32 + cc], s);
        h2[a][cc] = celu01(s);
    }
    __syncthreads();

    if (t < 64) {             // layer 3: 4 x 16
        int a = t >> 4, cc = t & 15;
        float s = b3[cc];
        #pragma unroll
        for (int r = 0; r < 32; ++r) s = fmaf(h2[a][r], W3[r*16 + cc], s);
        h3[a][cc] = celu01(s);
    }
    __syncthreads();

    if (t < 4) {              // layer 4 per atom
        float e = b4[0];
        #pragma unroll
        for (int r = 0; r < 16; ++r) e = fmaf(h3[t][r], W4[r], e);
        evals[t] = e;
    }
    __syncthreads();

    // ---- cross-block reduction via device-scope flags in d_ws ----
    if (grp != 0) {
        if (t == 0) {
            float v = (evals[0]+evals[1]) + (evals[2]+evals[3]);
            __hip_atomic_store(&partial[blk], v, __ATOMIC_RELAXED, __HIP_MEMORY_SCOPE_AGENT);
            __hip_atomic_store(&flags[blk], FLAG_MAGIC, __ATOMIC_RELEASE, __HIP_MEMORY_SCOPE_AGENT);
        }
    } else {
        if (t == 0) peers[0] = (evals[0]+evals[1]) + (evals[2]+evals[3]);
        if (t >= 1 && t < 8) {
            int src = blk + t;   // b*8 + t
            while (__hip_atomic_load(&flags[src], __ATOMIC_ACQUIRE,
                                     __HIP_MEMORY_SCOPE_AGENT) != FLAG_MAGIC) { }
            peers[t] = __hip_atomic_load(&partial[src], __ATOMIC_RELAXED,
                                         __HIP_MEMORY_SCOPE_AGENT);
            __hip_atomic_store(&flags[src], 0, __ATOMIC_RELAXED,
                               __HIP_MEMORY_SCOPE_AGENT);   // known state for next call
        }
        __syncthreads();
        if (t == 0) {
            float s = ((peers[0]+peers[1]) + (peers[2]+peers[3]))
                    + ((peers[4]+peers[5]) + (peers[6]+peers[7]));
            out[b] = s;
        }
    }
}

extern "C" void kernel_launch(void* const* d_in, const int* in_sizes, int n_in,
                              void* d_out, int out_size, void* d_ws, size_t ws_size,
                              hipStream_t stream) {
    (void)in_sizes; (void)n_in; (void)ws_size; (void)out_size;
    const int*   species = (const int*)d_in[0];
    const float* coords  = (const float*)d_in[1];
    const int*   belong  = (const int*)d_in[2];
    const float* approx  = (const float*)d_in[3];
    const float* W1 = (const float*)d_in[4];  const float* b1 = (const float*)d_in[5];
    const float* W2 = (const float*)d_in[6];  const float* b2 = (const float*)d_in[7];
    const float* W3 = (const float*)d_in[8];  const float* b3 = (const float*)d_in[9];
    const float* W4 = (const float*)d_in[10]; const float* b4 = (const float*)d_in[11];
    float* partial = (float*)d_ws;                 // 256 floats
    int*   flags   = ((int*)d_ws) + 256;           // 256 ints
    float* out     = (float*)d_out;

    fused_kernel<<<NB * 8, 1024, 0, stream>>>(species, coords, belong, approx,
                                              W1, b1, W2, b2, W3, b3, W4, b4,
                                              partial, flags, out);
}